// Round 4
// baseline (530.774 us; speedup 1.0000x reference)
//
#include <hip/hip_runtime.h>
#include <math.h>

#define DIN 640
#define KHALF 320
#define DH 1024
#define DOUT 128
#define CODEDIM 256
#define NE 8
#define NB 8
#define NT 1024
#define TAU_INV 10.0f
#define FEPS 1e-8f

// out layout: full_output[8*1024*1024], aux[1], div[1], ent[8], mean[8], std[8]
#define AUX_OFF  8388608
#define DIV_OFF  8388609
#define ENT_OFF  8388610
#define MEAN_OFF 8388618
#define STD_OFF  8388626

// padded LDS strides (bytes): stride%128==8 -> conflict-free ds_read_b128 (r3 measured 0)
#define XS_STRIDE 648    // 320*2 + 8
#define HS_STRIDE 520    // 256*2 + 8

typedef __bf16 bf16;
typedef bf16 bf16x4 __attribute__((ext_vector_type(4)));
typedef bf16 bf16x8 __attribute__((ext_vector_type(8)));
typedef float f32x16 __attribute__((ext_vector_type(16)));

// ---------------- block reduction helpers (blockDim multiple of 64) ----------
__device__ __forceinline__ float blk_sum(float v, float* sb) {
  #pragma unroll
  for (int o = 32; o > 0; o >>= 1) v += __shfl_down(v, o, 64);
  __syncthreads();
  if ((threadIdx.x & 63) == 0) sb[threadIdx.x >> 6] = v;
  __syncthreads();
  float tot = 0.f;
  int nw = blockDim.x >> 6;
  for (int i = 0; i < nw; ++i) tot += sb[i];
  return tot;
}

__device__ __forceinline__ float blk_max(float v, float* sb) {
  #pragma unroll
  for (int o = 32; o > 0; o >>= 1) v = fmaxf(v, __shfl_down(v, o, 64));
  __syncthreads();
  if ((threadIdx.x & 63) == 0) sb[threadIdx.x >> 6] = v;
  __syncthreads();
  float m = -3.0e38f;
  int nw = blockDim.x >> 6;
  for (int i = 0; i < nw; ++i) m = fmaxf(m, sb[i]);
  return m;
}

// ---------------- importance softmax + entropy/mean/std ---------------------
__global__ void k_imp(const float* __restrict__ fi, float* __restrict__ imp,
                      float* __restrict__ out) {
  __shared__ float sb[8];
  int e = blockIdx.x, tid = threadIdx.x;
  int d2v = tid + 512;
  float v0 = fi[e*DIN + tid] * 2.0f;          // /temp, temp = 0.5
  float v1 = fi[e*DIN + tid + 256] * 2.0f;
  float v2 = (d2v < DIN) ? fi[e*DIN + d2v] * 2.0f : -3.0e38f;
  float m = blk_max(fmaxf(v0, fmaxf(v1, v2)), sb);
  float e0 = expf(v0 - m), e1 = expf(v1 - m);
  float e2 = (d2v < DIN) ? expf(v2 - m) : 0.f;
  float s = blk_sum(e0 + e1 + e2, sb);
  float inv = 1.0f / s;
  float p0 = e0*inv, p1 = e1*inv, p2 = e2*inv;
  imp[e*DIN + tid] = p0;
  imp[e*DIN + tid + 256] = p1;
  if (d2v < DIN) imp[e*DIN + d2v] = p2;
  float ok2 = (d2v < DIN) ? 1.f : 0.f;
  float sp  = p0 + p1 + ok2*p2;
  float sp2 = p0*p0 + p1*p1 + ok2*p2*p2;
  float se  = p0*logf(p0 + FEPS) + p1*logf(p1 + FEPS) + ok2*p2*logf(p2 + FEPS);
  sp  = blk_sum(sp, sb);
  sp2 = blk_sum(sp2, sb);
  se  = blk_sum(se, sb);
  if (tid == 0) {
    out[ENT_OFF + e]  = -se;
    out[MEAN_OFF + e] = sp * (1.0f/DIN);
    float var = (sp2 - sp*sp*(1.0f/DIN)) * (1.0f/(DIN-1));
    out[STD_OFF + e]  = sqrtf(fmaxf(var, 0.f));
  }
}

// ---------------- anchor normalize + diversity loss --------------------------
__global__ void k_anchor_div(const float* __restrict__ ca, const float* __restrict__ fi,
                             float* __restrict__ anch, float* __restrict__ out) {
  __shared__ float sb[8];
  __shared__ float sd[256];
  int tid = threadIdx.x;
  for (int e = 0; e < NE; ++e) {
    float x = ca[e*CODEDIM + tid];
    float ss = blk_sum(x*x, sb);
    anch[e*CODEDIM + tid] = x / fmaxf(sqrtf(ss), 1e-12f);
  }
  // diversity: sim = fi @ fi^T, off-diag squared sum / 56
  int p = tid >> 2, q = tid & 3;     // pair p in 0..63, quarter q
  int i = p >> 3, j = p & 7;
  float dot = 0.f;
  for (int d = q*160; d < q*160 + 160; ++d) dot += fi[i*DIN + d] * fi[j*DIN + d];
  sd[tid] = dot;
  __syncthreads();
  if (tid < 64) {
    float s = sd[tid*4] + sd[tid*4+1] + sd[tid*4+2] + sd[tid*4+3];
    int ii = tid >> 3, jj = tid & 7;
    float val = (ii != jj) ? s*s : 0.f;
    #pragma unroll
    for (int o = 32; o > 0; o >>= 1) val += __shfl_down(val, o, 64);
    if (tid == 0) out[DIV_OFF] = val * (1.0f/56.0f);
  }
}

// -------- tiled transpose + f32->bf16 (+optional per-src-row scale) ----------
// src[e][R][C] -> dst[e][C][R]; dst[e][c][r] = src[e][r][c] * scale[e][r]
__global__ void k_transpose(const float* __restrict__ src, bf16* __restrict__ dst,
                            int R, int C, const float* __restrict__ scale) {
  __shared__ float tile[64][65];
  int c0 = blockIdx.x*64, r0 = blockIdx.y*64;
  int ee = blockIdx.z;
  const float* s = src + (size_t)ee*R*C;
  bf16* d = dst + (size_t)ee*C*R;
  int tx = threadIdx.x & 63, ty = threadIdx.x >> 6;
  #pragma unroll
  for (int p = 0; p < 16; ++p) {
    int r = p*4 + ty;
    tile[r][tx] = s[(size_t)(r0 + r)*C + c0 + tx];
  }
  __syncthreads();
  float sc = scale ? scale[(size_t)ee*R + r0 + tx] : 1.0f;
  #pragma unroll
  for (int p = 0; p < 16; ++p) {
    int cr = p*4 + ty;
    d[(size_t)(c0 + cr)*R + r0 + tx] = (bf16)(tile[tx][cr] * sc);
  }
}

// ---------------- router: cosine logits + gumbel softmax ---------------------
__global__ void k_router(const float* __restrict__ ce, const float* __restrict__ gn,
                         const float* __restrict__ anch, float* __restrict__ ew) {
  __shared__ float anc[NE*CODEDIM];
  int tid = threadIdx.x;
  for (int i2 = tid; i2 < NE*CODEDIM; i2 += 256) anc[i2] = anch[i2];
  __syncthreads();
  int wv = tid >> 6, lane = tid & 63;
  int token = blockIdx.x*4 + wv;
  float4 x = *(const float4*)(ce + (size_t)token*CODEDIM + lane*4);
  float ss = x.x*x.x + x.y*x.y + x.z*x.z + x.w*x.w;
  #pragma unroll
  for (int o = 1; o < 64; o <<= 1) ss += __shfl_xor(ss, o, 64);
  float inv = 1.0f / fmaxf(sqrtf(ss), 1e-12f);
  const float* g = gn + (size_t)token*NE;
  float z[8];
  float m = -3.0e38f;
  #pragma unroll
  for (int e2 = 0; e2 < NE; ++e2) {
    const float* a = anc + e2*CODEDIM + lane*4;
    float d = x.x*a[0] + x.y*a[1] + x.z*a[2] + x.w*a[3];
    #pragma unroll
    for (int o = 1; o < 64; o <<= 1) d += __shfl_xor(d, o, 64);
    z[e2] = (d*inv + g[e2]) * TAU_INV;
    m = fmaxf(m, z[e2]);
  }
  float ssum = 0.f;
  float pz[8];
  #pragma unroll
  for (int e2 = 0; e2 < NE; ++e2) { pz[e2] = expf(z[e2] - m); ssum += pz[e2]; }
  float num = 0.f;
  #pragma unroll
  for (int e2 = 0; e2 < NE; ++e2) num = (lane == e2) ? pz[e2] : num;  // static idx
  if (lane < NE) ew[(size_t)token*NE + lane] = num / ssum;
}

// ---------------- fused per-(b,e,64-token-tile) MoE MLP ----------------------
// Occupancy fix: X staged in two K=320 halves (40.5 KiB) + single H buffer
// (32.5 KiB) -> 74.7 KiB LDS -> 2 blocks/CU = 4 waves/SIMD (was 2).
// GEMM1 accumulators for all 4 col-passes stay live across the two K-halves
// (acc1[4][2] = 128 regs, unified VGPR/AGPR file). Loops are plain
// compiler-scheduled (round-3 lesson: hand-rolled reg pipelines regress).
// e = bid&7 pins each expert to one XCD -> weights L2-resident.
__global__ __launch_bounds__(512, 4)
void k_main(const float* __restrict__ h, const bf16* __restrict__ w1t,
            const bf16* __restrict__ w2t,
            const float* __restrict__ b1, const float* __restrict__ b2,
            const float* __restrict__ ew, float* __restrict__ out) {
  __shared__ bf16 XsF[64*(XS_STRIDE/2)];   // 41,472 B
  __shared__ bf16 HsF[64*(HS_STRIDE/2)];   // 33,280 B
  int bid = blockIdx.x;
  int e = bid & 7, tt = (bid >> 3) & 15, b = bid >> 7;
  int t0 = tt * 64;
  int tid = threadIdx.x;
  int lane = tid & 63, w = tid >> 6;
  int l31 = lane & 31, hh = lane >> 5;
  int rt = w >> 2, ct = w & 3;
  const char* Xb = (const char*)XsF;
  unsigned abaseX = (unsigned)(l31*XS_STRIDE + 16*hh);
  unsigned abaseH = (unsigned)((32*rt + l31)*HS_STRIDE + 16*hh);
  int colo = ct*32 + l31;                     // GEMM2 out col
  const bf16* w1e = w1t + (size_t)e*DH*DIN;
  const bf16* w2e = w2t + (size_t)e*DOUT*DH;
  const float* hb = h + (size_t)(b*NT + t0) * DIN;

  f32x16 acc1[4][2];
  #pragma unroll
  for (int p = 0; p < 4; ++p) { acc1[p][0] = (f32x16){}; acc1[p][1] = (f32x16){}; }
  f32x16 acc2 = {};

  #pragma unroll
  for (int kh = 0; kh < 2; ++kh) {
    if (kh) __syncthreads();               // all GEMM1 reads of Xs done before restage
    // stage X half = bf16(h[:, kh*320 .. +320)) (coalesced float4 reads)
    for (int i = tid; i < 64*(KHALF/4); i += 512) {
      int row = i / (KHALF/4);
      int c4 = (i - row*(KHALF/4)) * 4;
      float4 v = *(const float4*)(hb + (size_t)row*DIN + kh*KHALF + c4);
      bf16x4 bv;
      bv[0] = (bf16)v.x; bv[1] = (bf16)v.y; bv[2] = (bf16)v.z; bv[3] = (bf16)v.w;
      *(bf16x4*)((char*)XsF + row*XS_STRIDE + c4*2) = bv;
    }
    __syncthreads();
    #pragma unroll
    for (int p = 0; p < 4; ++p) {
      int colH = p*256 + w*32 + l31;        // this wave's GEMM1 col
      const bf16* pB = w1e + (size_t)colH*DIN + kh*KHALF + 8*hh;
      f32x16 a0 = acc1[p][0], a1 = acc1[p][1];
      #pragma unroll 4
      for (int ks = 0; ks < KHALF/16; ++ks) {
        unsigned ao = abaseX + 32u*ks;
        bf16x8 af0 = *(const bf16x8*)(Xb + ao);
        bf16x8 af1 = *(const bf16x8*)(Xb + ao + 32u*XS_STRIDE); // rows+32
        bf16x8 bfr = *(const bf16x8*)(pB + 16*ks);
        a0 = __builtin_amdgcn_mfma_f32_32x32x16_bf16(af0, bfr, a0, 0, 0, 0);
        a1 = __builtin_amdgcn_mfma_f32_32x32x16_bf16(af1, bfr, a1, 0, 0, 0);
      }
      acc1[p][0] = a0; acc1[p][1] = a1;
    }
  }
  // H phase: per pass, epilogue -> Hs -> barrier -> GEMM2 partial -> barrier
  const bf16* pB2base = w2e + (size_t)colo*DH + 8*hh;
  int colc2 = (w*32 + l31)*2;
  #pragma unroll
  for (int p = 0; p < 4; ++p) {
    float bb1 = b1[e*DH + p*256 + w*32 + l31];
    f32x16 a0 = acc1[p][0], a1 = acc1[p][1];
    #pragma unroll
    for (int r = 0; r < 16; ++r) {
      int rowa = (r & 3) + 8*(r >> 2) + 4*hh;     // 0..31 (tile a)
      unsigned wb = (unsigned)(rowa*HS_STRIDE + colc2);
      float xa = a0[r] + bb1;
      float xb = a1[r] + bb1;
      float ga = 0.5f * xa * (1.0f + erff(xa * 0.70710678118654752f));
      float gb = 0.5f * xb * (1.0f + erff(xb * 0.70710678118654752f));
      *(bf16*)((char*)HsF + wb) = (bf16)ga;
      *(bf16*)((char*)HsF + wb + 32*HS_STRIDE) = (bf16)gb;  // rows+32
    }
    __syncthreads();
    const bf16* pB2 = pB2base + p*256;
    #pragma unroll 4
    for (int kk = 0; kk < 16; ++kk) {
      bf16x8 a2 = *(const bf16x8*)((const char*)HsF + abaseH + 32u*kk);
      bf16x8 b2r = *(const bf16x8*)(pB2 + 16*kk);
      acc2 = __builtin_amdgcn_mfma_f32_32x32x16_bf16(a2, b2r, acc2, 0, 0, 0);
    }
    if (p < 3) __syncthreads();            // before next pass overwrites Hs
  }
  float bb2 = b2[e*DOUT + colo];
  #pragma unroll
  for (int r = 0; r < 16; ++r) {
    int rowa = 32*rt + (r & 3) + 8*(r >> 2) + 4*hh;
    int t = t0 + rowa;
    float gate = ew[(size_t)(b*NT + t)*NE + e];
    out[(size_t)(b*NT + t)*(NE*DOUT) + e*DOUT + colo] = (acc2[r] + bb2) * gate;
  }
}

// ---------------- expert counts + partial sums --------------------------------
__global__ void k_counts(const float* __restrict__ ew, float* __restrict__ counts,
                         float* __restrict__ partials) {
  __shared__ float sb[4];
  int g2 = blockIdx.x*256 + threadIdx.x;   // (t,e) flat, 0..8191
  float c = 0.f;
  #pragma unroll
  for (int b = 0; b < NB; ++b) c += ew[b*(NT*NE) + g2];
  counts[g2] = c;
  float tot = blk_sum(c, sb);
  if (threadIdx.x == 0) partials[blockIdx.x] = tot;
}

// ---------------- aux loss ----------------------------------------------------
__global__ void k_aux(const float* __restrict__ counts, const float* __restrict__ partials,
                      float* __restrict__ out) {
  __shared__ float sb[4];
  int tid = threadIdx.x;
  float pv = (tid < 32) ? partials[tid] : 0.f;
  float total = blk_sum(pv, sb);
  float invt = 1.0f / (total + FEPS);
  float sq = 0.f, ent = 0.f;
  for (int i2 = tid; i2 < NT*NE; i2 += 256) {
    float c = counts[i2];
    sq += c*c;
    float ld = c * invt;
    ent -= ld * logf(ld + FEPS);
  }
  sq = blk_sum(sq, sb);
  ent = blk_sum(ent, sb);
  if (tid == 0) {
    float var = (sq - total*total*(1.0f/(NT*NE))) * (1.0f/(NT*NE - 1));
    float stdv = sqrtf(fmaxf(var, 0.f));
    float ment = 0.f;
    #pragma unroll
    for (int e2 = 0; e2 < NE; ++e2) ment += out[ENT_OFF + e2];
    ment *= (1.0f/NE);
    out[AUX_OFF] = 0.5f*(stdv + ent) + 0.01f*ment;
  }
}

// ---------------- launch ------------------------------------------------------
extern "C" void kernel_launch(void* const* d_in, const int* in_sizes, int n_in,
                              void* d_out, int out_size, void* d_ws, size_t ws_size,
                              hipStream_t stream) {
  const float* h  = (const float*)d_in[0];
  const float* ce = (const float*)d_in[1];
  const float* gn = (const float*)d_in[2];
  const float* ca = (const float*)d_in[3];
  const float* fi = (const float*)d_in[4];
  const float* W1 = (const float*)d_in[5];
  const float* b1 = (const float*)d_in[6];
  const float* W2 = (const float*)d_in[7];
  const float* b2 = (const float*)d_in[8];
  float* out = (float*)d_out;
  char* ws = (char*)d_ws;
  // ws layout (bytes)
  bf16*  w1t      = (bf16*)(ws);                 // [E][DH][DIN] bf16 (imp-folded): 10,485,760
  bf16*  w2t      = (bf16*)(ws + 10485760);      // [E][DOUT][DH] bf16: 2,097,152
  float* imp      = (float*)(ws + 12582912);     // [E][DIN]: 20,480
  float* anch     = (float*)(ws + 12603392);     // [E][CODE]: 8,192
  float* ew       = (float*)(ws + 12611584);     // [B][T][E]: 262,144
  float* counts   = (float*)(ws + 12873728);     // [T*E]: 32,768
  float* partials = (float*)(ws + 12906496);     // [32]

  k_imp<<<dim3(8), dim3(256), 0, stream>>>(fi, imp, out);
  k_anchor_div<<<dim3(1), dim3(256), 0, stream>>>(ca, fi, anch, out);
  k_transpose<<<dim3(16, 10, 8), dim3(256), 0, stream>>>(W1, w1t, 640, 1024, imp);
  k_transpose<<<dim3(2, 16, 8), dim3(256), 0, stream>>>(W2, w2t, 1024, 128, nullptr);
  k_router<<<dim3(2048), dim3(256), 0, stream>>>(ce, gn, anch, ew);
  k_main<<<dim3(1024), dim3(512), 0, stream>>>(h, w1t, w2t, b1, b2, ew, out);
  k_counts<<<dim3(32), dim3(256), 0, stream>>>(ew, counts, partials);
  k_aux<<<dim3(1), dim3(256), 0, stream>>>(counts, partials, out);
}

// Round 5
// 258.387 us; speedup vs baseline: 2.0542x; 2.0542x over previous
//
#include <hip/hip_runtime.h>
#include <math.h>

#define DIN 640
#define DH 1024
#define DOUT 128
#define CODEDIM 256
#define NE 8
#define NB 8
#define NT 1024
#define TAU_INV 10.0f
#define FEPS 1e-8f

// out layout: full_output[8*1024*1024], aux[1], div[1], ent[8], mean[8], std[8]
#define AUX_OFF  8388608
#define DIV_OFF  8388609
#define ENT_OFF  8388610
#define MEAN_OFF 8388618
#define STD_OFF  8388626

typedef __bf16 bf16;
typedef bf16 bf16x4 __attribute__((ext_vector_type(4)));
typedef bf16 bf16x8 __attribute__((ext_vector_type(8)));
typedef float f32x16 __attribute__((ext_vector_type(16)));

#define BAR() do { asm volatile("" ::: "memory"); __builtin_amdgcn_s_barrier(); asm volatile("" ::: "memory"); } while(0)
#define VMCNT3 asm volatile("s_waitcnt vmcnt(3)" ::: "memory")
#define VMCNT0 asm volatile("s_waitcnt vmcnt(0)" ::: "memory")
#define LGKM0  asm volatile("s_waitcnt lgkmcnt(0)" ::: "memory")

// async global->LDS, 16B per lane; lds dest must be wave-uniform base (HW adds lane*16)
__device__ __forceinline__ void gload16(const void* g, void* l) {
  __builtin_amdgcn_global_load_lds(
      (const __attribute__((address_space(1))) unsigned int*)g,
      (__attribute__((address_space(3))) unsigned int*)l, 16, 0, 0);
}

// ---------------- block reduction helpers (blockDim multiple of 64) ----------
__device__ __forceinline__ float blk_sum(float v, float* sb) {
  #pragma unroll
  for (int o = 32; o > 0; o >>= 1) v += __shfl_down(v, o, 64);
  __syncthreads();
  if ((threadIdx.x & 63) == 0) sb[threadIdx.x >> 6] = v;
  __syncthreads();
  float tot = 0.f;
  int nw = blockDim.x >> 6;
  for (int i = 0; i < nw; ++i) tot += sb[i];
  return tot;
}

__device__ __forceinline__ float blk_max(float v, float* sb) {
  #pragma unroll
  for (int o = 32; o > 0; o >>= 1) v = fmaxf(v, __shfl_down(v, o, 64));
  __syncthreads();
  if ((threadIdx.x & 63) == 0) sb[threadIdx.x >> 6] = v;
  __syncthreads();
  float m = -3.0e38f;
  int nw = blockDim.x >> 6;
  for (int i = 0; i < nw; ++i) m = fmaxf(m, sb[i]);
  return m;
}

// ---------------- importance softmax + entropy/mean/std ---------------------
__global__ void k_imp(const float* __restrict__ fi, float* __restrict__ imp,
                      float* __restrict__ out) {
  __shared__ float sb[8];
  int e = blockIdx.x, tid = threadIdx.x;
  int d2v = tid + 512;
  float v0 = fi[e*DIN + tid] * 2.0f;          // /temp, temp = 0.5
  float v1 = fi[e*DIN + tid + 256] * 2.0f;
  float v2 = (d2v < DIN) ? fi[e*DIN + d2v] * 2.0f : -3.0e38f;
  float m = blk_max(fmaxf(v0, fmaxf(v1, v2)), sb);
  float e0 = expf(v0 - m), e1 = expf(v1 - m);
  float e2 = (d2v < DIN) ? expf(v2 - m) : 0.f;
  float s = blk_sum(e0 + e1 + e2, sb);
  float inv = 1.0f / s;
  float p0 = e0*inv, p1 = e1*inv, p2 = e2*inv;
  imp[e*DIN + tid] = p0;
  imp[e*DIN + tid + 256] = p1;
  if (d2v < DIN) imp[e*DIN + d2v] = p2;
  float ok2 = (d2v < DIN) ? 1.f : 0.f;
  float sp  = p0 + p1 + ok2*p2;
  float sp2 = p0*p0 + p1*p1 + ok2*p2*p2;
  float se  = p0*logf(p0 + FEPS) + p1*logf(p1 + FEPS) + ok2*p2*logf(p2 + FEPS);
  sp  = blk_sum(sp, sb);
  sp2 = blk_sum(sp2, sb);
  se  = blk_sum(se, sb);
  if (tid == 0) {
    out[ENT_OFF + e]  = -se;
    out[MEAN_OFF + e] = sp * (1.0f/DIN);
    float var = (sp2 - sp*sp*(1.0f/DIN)) * (1.0f/(DIN-1));
    out[STD_OFF + e]  = sqrtf(fmaxf(var, 0.f));
  }
}

// ---------------- anchor normalize + diversity loss --------------------------
__global__ void k_anchor_div(const float* __restrict__ ca, const float* __restrict__ fi,
                             float* __restrict__ anch, float* __restrict__ out) {
  __shared__ float sb[8];
  __shared__ float sd[256];
  int tid = threadIdx.x;
  for (int e = 0; e < NE; ++e) {
    float x = ca[e*CODEDIM + tid];
    float ss = blk_sum(x*x, sb);
    anch[e*CODEDIM + tid] = x / fmaxf(sqrtf(ss), 1e-12f);
  }
  // diversity: sim = fi @ fi^T, off-diag squared sum / 56
  int p = tid >> 2, q = tid & 3;     // pair p in 0..63, quarter q
  int i = p >> 3, j = p & 7;
  float dot = 0.f;
  for (int d = q*160; d < q*160 + 160; ++d) dot += fi[i*DIN + d] * fi[j*DIN + d];
  sd[tid] = dot;
  __syncthreads();
  if (tid < 64) {
    float s = sd[tid*4] + sd[tid*4+1] + sd[tid*4+2] + sd[tid*4+3];
    int ii = tid >> 3, jj = tid & 7;
    float val = (ii != jj) ? s*s : 0.f;
    #pragma unroll
    for (int o = 32; o > 0; o >>= 1) val += __shfl_down(val, o, 64);
    if (tid == 0) out[DIV_OFF] = val * (1.0f/56.0f);
  }
}

// -------- tiled transpose + f32->bf16 (+optional per-src-row scale) ----------
// src[e][R][C] -> dst[e][C][R]; dst[e][c][r] = src[e][r][c] * scale[e][r]
__global__ void k_transpose(const float* __restrict__ src, bf16* __restrict__ dst,
                            int R, int C, const float* __restrict__ scale) {
  __shared__ float tile[64][65];
  int c0 = blockIdx.x*64, r0 = blockIdx.y*64;
  int ee = blockIdx.z;
  const float* s = src + (size_t)ee*R*C;
  bf16* d = dst + (size_t)ee*C*R;
  int tx = threadIdx.x & 63, ty = threadIdx.x >> 6;
  #pragma unroll
  for (int p = 0; p < 16; ++p) {
    int r = p*4 + ty;
    tile[r][tx] = s[(size_t)(r0 + r)*C + c0 + tx];
  }
  __syncthreads();
  float sc = scale ? scale[(size_t)ee*R + r0 + tx] : 1.0f;
  #pragma unroll
  for (int p = 0; p < 16; ++p) {
    int cr = p*4 + ty;
    d[(size_t)(c0 + cr)*R + r0 + tx] = (bf16)(tile[tx][cr] * sc);
  }
}

// ---------------- h f32 -> bf16 (row-major, shared across experts) -----------
__global__ void k_h2b(const float* __restrict__ h, bf16* __restrict__ xb) {
  size_t i = (size_t)blockIdx.x*256 + threadIdx.x;   // 8 elements per thread
  const float4* p = (const float4*)(h + i*8);
  float4 v0 = p[0], v1 = p[1];
  bf16x8 o;
  o[0]=(bf16)v0.x; o[1]=(bf16)v0.y; o[2]=(bf16)v0.z; o[3]=(bf16)v0.w;
  o[4]=(bf16)v1.x; o[5]=(bf16)v1.y; o[6]=(bf16)v1.z; o[7]=(bf16)v1.w;
  *(bf16x8*)(xb + i*8) = o;
}

// ---------------- router: cosine logits + gumbel softmax ---------------------
__global__ void k_router(const float* __restrict__ ce, const float* __restrict__ gn,
                         const float* __restrict__ anch, float* __restrict__ ew) {
  __shared__ float anc[NE*CODEDIM];
  int tid = threadIdx.x;
  for (int i2 = tid; i2 < NE*CODEDIM; i2 += 256) anc[i2] = anch[i2];
  __syncthreads();
  int wv = tid >> 6, lane = tid & 63;
  int token = blockIdx.x*4 + wv;
  float4 x = *(const float4*)(ce + (size_t)token*CODEDIM + lane*4);
  float ss = x.x*x.x + x.y*x.y + x.z*x.z + x.w*x.w;
  #pragma unroll
  for (int o = 1; o < 64; o <<= 1) ss += __shfl_xor(ss, o, 64);
  float inv = 1.0f / fmaxf(sqrtf(ss), 1e-12f);
  const float* g = gn + (size_t)token*NE;
  float z[8];
  float m = -3.0e38f;
  #pragma unroll
  for (int e2 = 0; e2 < NE; ++e2) {
    const float* a = anc + e2*CODEDIM + lane*4;
    float d = x.x*a[0] + x.y*a[1] + x.z*a[2] + x.w*a[3];
    #pragma unroll
    for (int o = 1; o < 64; o <<= 1) d += __shfl_xor(d, o, 64);
    z[e2] = (d*inv + g[e2]) * TAU_INV;
    m = fmaxf(m, z[e2]);
  }
  float ssum = 0.f;
  float pz[8];
  #pragma unroll
  for (int e2 = 0; e2 < NE; ++e2) { pz[e2] = expf(z[e2] - m); ssum += pz[e2]; }
  float num = 0.f;
  #pragma unroll
  for (int e2 = 0; e2 < NE; ++e2) num = (lane == e2) ? pz[e2] : num;  // static idx
  if (lane < NE) ew[(size_t)token*NE + lane] = num / ssum;
}

// ---------------- fused MoE MLP: canonical async-staged GEMM ----------------
// block = (expert e = bid&7 [XCD-pinned], 64-token M-tile mt = bid>>3).
// 8 DH-chunks x 10 K-steps (BK=64): global_load_lds A(8KB)+B(16KB) dbuf,
// counted vmcnt(3), raw barriers; 4 MFMA + 8 ds_read_b128 per wave/K-step.
// GELU -> Hs(16KB LDS) -> GEMM2 accumulates acc2 (only long-lived regs).
// LDS 64KB -> 2 blocks/CU = 4 waves/SIMD; live VGPR ~90 < 128 cap.
// XOR-swizzle (T21): linear gload dest + inverse-swizzled SOURCE + swizzled reads.
__global__ __launch_bounds__(512, 4)
void k_main(const bf16* __restrict__ xb, const bf16* __restrict__ w1t,
            const bf16* __restrict__ w2t,
            const float* __restrict__ b1, const float* __restrict__ b2,
            const float* __restrict__ ew, float* __restrict__ out) {
  __shared__ char Ab[2][8192];     // [64 rows][128 B] X-tile
  __shared__ char Bb[2][16384];    // [128 rows][128 B] W1-tile
  __shared__ char Hs[16384];       // [64 rows][256 B] H-chunk
  const int bid = blockIdx.x;
  const int e = bid & 7;
  const int mt = bid >> 3;               // 0..127
  const int M0 = mt * 64;
  const int tid = threadIdx.x;
  const int lane = tid & 63, w = tid >> 6;
  const int l31 = lane & 31, hh = lane >> 5;
  const int rh = w >> 2, c4 = w & 3;     // 2 row-groups x 4 col-tiles
  const unsigned xsw = (unsigned)((l31 & 7) << 4);
  const unsigned baseA = (unsigned)((32*rh + l31)*128 + hh*16);
  const unsigned baseB = (unsigned)((32*c4 + l31)*128 + hh*16);
  const unsigned baseH = (unsigned)((32*rh + l31)*256 + hh*16);
  const char* xby = (const char*)xb;
  const char* w1y = (const char*)w1t;
  // staging source addresses (per-lane, inverse-swizzled; involution q(q(p))=p)
  unsigned pA = (unsigned)(w*1024 + lane*16);
  unsigned qA = pA ^ ((pA >> 3) & 0x70u);
  const size_t gA0 = (size_t)(M0 + (int)(qA >> 7)) * (DIN*2) + (qA & 127);
  unsigned pB0 = (unsigned)((2*w + 0)*1024 + lane*16);
  unsigned qB0 = pB0 ^ ((pB0 >> 3) & 0x70u);
  unsigned pB1 = (unsigned)((2*w + 1)*1024 + lane*16);
  unsigned qB1 = pB1 ^ ((pB1 >> 3) & 0x70u);
  const size_t gB0 = (size_t)(e*DH + (int)(qB0 >> 7)) * (DIN*2) + (qB0 & 127);
  const size_t gB1 = (size_t)(e*DH + (int)(qB1 >> 7)) * (DIN*2) + (qB1 & 127);

  auto STAGE = [&](int buf, int nch, int t) {
    size_t ko = (size_t)t * 128;                      // K-window byte offset
    size_t no = (size_t)(nch * 128) * (DIN*2);        // B n-window row offset
    gload16(xby + gA0 + ko, &Ab[buf][w*1024]);
    gload16(w1y + gB0 + no + ko, &Bb[buf][(2*w + 0)*1024]);
    gload16(w1y + gB1 + no + ko, &Bb[buf][(2*w + 1)*1024]);
  };

  f32x16 acc2 = {};
  int cur = 0;
  STAGE(0, 0, 0);
  VMCNT0;
  BAR();
  for (int nch = 0; nch < 8; ++nch) {
    f32x16 acc1 = {};
    for (int t = 0; t < 10; ++t) {
      int nn = (t == 9) ? nch + 1 : nch;
      int t2 = (t == 9) ? 0 : t + 1;
      if (nn < 8) {
        STAGE(cur ^ 1, nn, t2);
        VMCNT3;                 // keep the 3 new loads in flight; old 3 done
      } else {
        VMCNT0;
      }
      BAR();
      const char* Ac = Ab[cur];
      const char* Bc = Bb[cur];
      #pragma unroll
      for (int ks = 0; ks < 4; ++ks) {
        bf16x8 a = *(const bf16x8*)(Ac + ((baseA + 32u*ks) ^ xsw));
        bf16x8 b = *(const bf16x8*)(Bc + ((baseB + 32u*ks) ^ xsw));
        acc1 = __builtin_amdgcn_mfma_f32_32x32x16_bf16(a, b, acc1, 0, 0, 0);
      }
      BAR();
      cur ^= 1;
    }
    // epilogue: +b1, exact GELU, bf16 -> Hs (swizzled scalar writes)
    float bb1 = b1[e*DH + nch*128 + 32*c4 + l31];
    #pragma unroll
    for (int r = 0; r < 16; ++r) {
      int rowa = 32*rh + (r & 3) + 8*(r >> 2) + 4*hh;
      unsigned lg = (unsigned)(rowa*256 + (32*c4 + l31)*2);
      unsigned ph = lg ^ ((unsigned)(rowa & 7) << 4);
      float xv = acc1[r] + bb1;
      float gv = 0.5f * xv * (1.0f + erff(xv * 0.70710678118654752f));
      *(bf16*)(Hs + ph) = (bf16)gv;
    }
    LGKM0;          // raw barrier does NOT drain lgkm: flush ds_writes first
    BAR();
    // GEMM2 partial over this 128-col slab (B2 frags from L2-resident W2)
    const bf16* pB2 = w2t + ((size_t)(e*DOUT + 32*c4 + l31))*DH + nch*128 + 8*hh;
    #pragma unroll
    for (int kk = 0; kk < 8; ++kk) {
      bf16x8 a2 = *(const bf16x8*)(Hs + ((baseH + 32u*kk) ^ xsw));
      bf16x8 b2f = *(const bf16x8*)(pB2 + 16*kk);
      acc2 = __builtin_amdgcn_mfma_f32_32x32x16_bf16(a2, b2f, acc2, 0, 0, 0);
    }
  }
  // output: +b2, *gate, f32 store
  float bb2 = b2[e*DOUT + 32*c4 + l31];
  #pragma unroll
  for (int r = 0; r < 16; ++r) {
    int rowa = 32*rh + (r & 3) + 8*(r >> 2) + 4*hh;
    int m = M0 + rowa;
    float gate = ew[(size_t)m*NE + e];
    out[(size_t)m*(NE*DOUT) + e*DOUT + 32*c4 + l31] = (acc2[r] + bb2) * gate;
  }
}

// ---------------- expert counts + partial sums --------------------------------
__global__ void k_counts(const float* __restrict__ ew, float* __restrict__ counts,
                         float* __restrict__ partials) {
  __shared__ float sb[4];
  int g2 = blockIdx.x*256 + threadIdx.x;   // (t,e) flat, 0..8191
  float c = 0.f;
  #pragma unroll
  for (int b = 0; b < NB; ++b) c += ew[b*(NT*NE) + g2];
  counts[g2] = c;
  float tot = blk_sum(c, sb);
  if (threadIdx.x == 0) partials[blockIdx.x] = tot;
}

// ---------------- aux loss ----------------------------------------------------
__global__ void k_aux(const float* __restrict__ counts, const float* __restrict__ partials,
                      float* __restrict__ out) {
  __shared__ float sb[4];
  int tid = threadIdx.x;
  float pv = (tid < 32) ? partials[tid] : 0.f;
  float total = blk_sum(pv, sb);
  float invt = 1.0f / (total + FEPS);
  float sq = 0.f, ent = 0.f;
  for (int i2 = tid; i2 < NT*NE; i2 += 256) {
    float c = counts[i2];
    sq += c*c;
    float ld = c * invt;
    ent -= ld * logf(ld + FEPS);
  }
  sq = blk_sum(sq, sb);
  ent = blk_sum(ent, sb);
  if (tid == 0) {
    float var = (sq - total*total*(1.0f/(NT*NE))) * (1.0f/(NT*NE - 1));
    float stdv = sqrtf(fmaxf(var, 0.f));
    float ment = 0.f;
    #pragma unroll
    for (int e2 = 0; e2 < NE; ++e2) ment += out[ENT_OFF + e2];
    ment *= (1.0f/NE);
    out[AUX_OFF] = 0.5f*(stdv + ent) + 0.01f*ment;
  }
}

// ---------------- launch ------------------------------------------------------
extern "C" void kernel_launch(void* const* d_in, const int* in_sizes, int n_in,
                              void* d_out, int out_size, void* d_ws, size_t ws_size,
                              hipStream_t stream) {
  const float* h  = (const float*)d_in[0];
  const float* ce = (const float*)d_in[1];
  const float* gn = (const float*)d_in[2];
  const float* ca = (const float*)d_in[3];
  const float* fi = (const float*)d_in[4];
  const float* W1 = (const float*)d_in[5];
  const float* b1 = (const float*)d_in[6];
  const float* W2 = (const float*)d_in[7];
  const float* b2 = (const float*)d_in[8];
  float* out = (float*)d_out;
  char* ws = (char*)d_ws;
  // ws layout (bytes)
  bf16*  w1t      = (bf16*)(ws);                 // [E][DH][DIN] bf16 (imp-folded): 10,485,760
  bf16*  w2t      = (bf16*)(ws + 10485760);      // [E][DOUT][DH] bf16: 2,097,152
  bf16*  xbuf     = (bf16*)(ws + 12582912);      // [8192][640] bf16: 10,485,760
  float* imp      = (float*)(ws + 23068672);     // [E][DIN]: 20,480
  float* anch     = (float*)(ws + 23089152);     // [E][CODE]: 8,192
  float* ew       = (float*)(ws + 23097344);     // [B][T][E]: 262,144
  float* counts   = (float*)(ws + 23359488);     // [T*E]: 32,768
  float* partials = (float*)(ws + 23392256);     // [32]

  k_imp<<<dim3(8), dim3(256), 0, stream>>>(fi, imp, out);
  k_anchor_div<<<dim3(1), dim3(256), 0, stream>>>(ca, fi, anch, out);
  k_transpose<<<dim3(16, 10, 8), dim3(256), 0, stream>>>(W1, w1t, 640, 1024, imp);
  k_transpose<<<dim3(2, 16, 8), dim3(256), 0, stream>>>(W2, w2t, 1024, 128, nullptr);
  k_h2b<<<dim3(2560), dim3(256), 0, stream>>>(h, xbuf);
  k_router<<<dim3(2048), dim3(256), 0, stream>>>(ce, gn, anch, ew);
  k_main<<<dim3(1024), dim3(512), 0, stream>>>(xbuf, w1t, w2t, b1, b2, ew, out);
  k_counts<<<dim3(32), dim3(256), 0, stream>>>(ew, counts, partials);
  k_aux<<<dim3(1), dim3(256), 0, stream>>>(counts, partials, out);
}